// Round 5
// baseline (3232.455 us; speedup 1.0000x reference)
//
#include <hip/hip_runtime.h>
#include <math.h>

#define NN 4096
#define TT 64
#define HH 128
#define NNP 4160            // hinT row stride (shorts): 8320B kills 8KB L2 set-aliasing
#define SPLITS 16
#define KPB (NN / SPLITS)   // 256 keys per phase-A block
#define KT 32
#define NTILES (KPB / KT)   // 8
#define SCALE 0.08838834764831845f   // 1/sqrt(128)
#define CSHIFT 16.0f

typedef __attribute__((ext_vector_type(8))) short short8;
typedef __attribute__((ext_vector_type(4))) float f32x4;
typedef unsigned long long u64;
#define MFMA(a, b, c)   __builtin_amdgcn_mfma_f32_16x16x32_bf16((a), (b), (c), 0, 0, 0)

// ---- bf16 helpers (RNE) ----
__device__ __forceinline__ short f2b(float f) {
    union { float f; unsigned u; } v; v.f = f;
    unsigned r = v.u + 0x7fffu + ((v.u >> 16) & 1u);
    return (short)(r >> 16);
}
__device__ __forceinline__ float b2f(short s) {
    union { unsigned u; float f; } v; v.u = ((unsigned)(unsigned short)s) << 16;
    return v.f;
}
// Wave-local LDS fence (R7/R8-proven): completes ds ops + blocks compiler
// reordering of cross-lane LDS accesses without a block barrier.
__device__ __forceinline__ void lds_fence() {
    __asm__ __volatile__("s_waitcnt lgkmcnt(0)" ::: "memory");
}

// ===========================================================================
// hinT column permutation sigma (within each 32-column group):
//   column c holds node  sigma(c) = (c&4) ? 16 + 4*(c>>3) + (c&3)
//                                         :      4*(c>>3) + (c&3)
// Writers (prep/fuse) place node kk at column
//   inv_sigma(kk) = ((kk>>2)&3)*8 + ((kk>>4)&1)*4 + (kk&3).
// After swapped QK^T (st = MFMA(K,Q), D[key][q]), lane (ln,g) holds the 8
// P-values of query qt*16+ln for keys {4g..4g+3, 16+4g..16+4g+3} — exactly a
// 16x16x32 PV A-fragment under sigma on the key axis.  PV's key axis is a dot
// product, so permuting BOTH P-slots and V-slots by sigma is free; baking
// sigma into hinT storage means attention reads V contiguously and P never
// leaves registers.  (R3-proven end to end, scalar f2b packing.)
// NOTE (R4 post-mortem): v_cvt_pk_bf16_f32 inline asm was the common factor
// of all three NaN rounds — packing stays scalar f2b (proven) here.
// ===========================================================================

// ===========================================================================
// prep: once per launch. bf16 weight transposes; hp = b_proj (h0=0);
// hinT (padded stride NNP, sigma-permuted columns) from x[:,0], m[:,0].
// ===========================================================================
__global__ __launch_bounds__(256) void prep_kernel(
    const float* __restrict__ x_seq, const float* __restrict__ m_seq,
    const float* __restrict__ W_in,  const float* __restrict__ b_in,
    const float* __restrict__ W_proj,const float* __restrict__ b_proj,
    const float* __restrict__ W_gcn,
    short* __restrict__ hp, short* __restrict__ hinT,
    short* __restrict__ WgT, short* __restrict__ WpT)
{
    const int b = blockIdx.x, tid = threadIdx.x;
    if (b < 256) {
        const int n0 = b * 16;
        for (int i = tid; i < 16 * HH; i += 256) {
            const int q = i >> 7, j = i & 127, n = n0 + q;
            hp[n * HH + j] = f2b(b_proj[j]);
            float hv = x_seq[n * TT] * W_in[j] + m_seq[n * TT] * W_in[HH + j] + b_in[j];
            hv = hv > 0.f ? hv : 0.f;
            // col = (n & ~31) | inv_sigma(n & 31)
            const int col = (n & ~31) | (((n >> 2) & 3) << 3) | (((n >> 4) & 1) << 2) | (n & 3);
            hinT[(size_t)j * NNP + col] = f2b(hv);
        }
    } else {
        const int wb = b - 256;
        #pragma unroll
        for (int k = 0; k < 4; ++k) {
            const int idx = wb * 1024 + k * 256 + tid;   // = n*128 + kk
            const int n = idx >> 7, kk = idx & 127;
            WgT[idx] = f2b(W_gcn[kk * HH + n]);
            WpT[idx] = f2b(W_proj[kk * HH + n]);
        }
    }
}

// ===========================================================================
// Phase A: attention partials. 256 blocks (16 qg x 16 splits) x 512 thr
// (8 waves), waves FULLY INDEPENDENT — no LDS staging, no barriers.
// K/V fragments stream straight from global: hp+hinT are 2 MB total (L2-
// resident per XCD); all 8 waves of a CU read identical fragments, so L1
// captures cross-wave reuse.  K-frags register-prefetched one tile ahead via
// an explicitly 2x-unrolled loop with NAMED kf0/kf1 buffers (no runtime
// array selection -> no scratch).  V-frag latency hides under QK^T+softmax.
//   QK^T swapped: st = MFMA(kf, qf) -> D[key][q].  P rounds to bf16 via
//   scalar f2b (R3-proven) and feeds PV directly as the A-fragment (sigma).
//   l accumulates on the MATRIX pipe: a 9th accumulator with B = all-ones —
//   layout-independent (B=1 makes any operand convention sum all k-slots);
//   same rounded p values as R3's VALU sum (self-consistency preserved).
// Partial O goes out bf16 via the per-wave LDS bounce (coalesced 16B/lane).
// ===========================================================================
__global__ __launch_bounds__(512, 2) void attn_kernel(
    const short* __restrict__ hp, const short* __restrict__ hinT,
    short* __restrict__ OpartB, float* __restrict__ lpart)
{
    __shared__ __align__(16) short bounce_s[8 * 2048];   // 32 KB, wave-private 4KB slices

    const int tid  = threadIdx.x;
    const int wave = tid >> 6, lane = tid & 63;
    const int ln = lane & 15, g = lane >> 4;
    const int qg = blockIdx.x >> 4, split = blockIdx.x & 15;
    const int q0 = qg * 256 + wave * 32;
    const int kbase = split * KPB;

    // Q fragments (B-operand in swapped QK^T): 2 q-tiles, proven layout
    short8 qf[2][4];
    #pragma unroll
    for (int qt = 0; qt < 2; ++qt)
        #pragma unroll
        for (int kc = 0; kc < 4; ++kc)
            qf[qt][kc] = *(const short8*)&hp[(q0 + qt * 16 + ln) * HH + kc * 32 + g * 8];

    // oacc[qt][0..7] = O[q][d];  lacc[qt] = l (ones-column accumulator)
    f32x4 oacc[2][8] = {};
    f32x4 lacc[2] = {};
    short8 vone;
    #pragma unroll
    for (int e = 0; e < 8; ++e) vone[e] = (short)0x3F80;   // bf16 1.0

    short8 kf0[2][4], kf1[2][4];
    #pragma unroll
    for (int kt2 = 0; kt2 < 2; ++kt2)
        #pragma unroll
        for (int kc = 0; kc < 4; ++kc)
            kf0[kt2][kc] = *(const short8*)&hp[(kbase + kt2 * 16 + ln) * HH + kc * 32 + g * 8];

    // one K/V tile: V frags direct from global; prefetch next K into kfn;
    // QK^T -> f2b softmax numerators -> PV (+ ones-column l).
    auto tile_body = [&](int kb, short8 (&kfc)[2][4], short8 (&kfn)[2][4],
                         bool pf, int kn) {
        short8 vf[8];
        #pragma unroll
        for (int dt = 0; dt < 8; ++dt)
            vf[dt] = *(const short8*)&hinT[(size_t)(dt * 16 + ln) * NNP + kb + g * 8];

        if (pf) {
            #pragma unroll
            for (int kt2 = 0; kt2 < 2; ++kt2)
                #pragma unroll
                for (int kc = 0; kc < 4; ++kc)
                    kfn[kt2][kc] = *(const short8*)&hp[(kn + kt2 * 16 + ln) * HH + kc * 32 + g * 8];
        }

        // swapped scores: st[kt2][qt][r] = S[key = kt2*16+g*4+r][q = qt*16+ln]
        f32x4 st[2][2] = {};
        __builtin_amdgcn_s_setprio(1);
        #pragma unroll
        for (int kt2 = 0; kt2 < 2; ++kt2)
            #pragma unroll
            for (int qt = 0; qt < 2; ++qt)
                #pragma unroll
                for (int kc = 0; kc < 4; ++kc)
                    st[kt2][qt] = MFMA(kfc[kt2][kc], qf[qt][kc], st[kt2][qt]);
        __builtin_amdgcn_s_setprio(0);

        // fixed-shift softmax numerators -> bf16 A-fragments (R3-proven order)
        short8 pa[2];
        #pragma unroll
        for (int qt = 0; qt < 2; ++qt) {
            short8 paq;
            #pragma unroll
            for (int e = 0; e < 8; ++e) {
                const float s = (e < 4) ? st[0][qt][e] : st[1][qt][e - 4];
                paq[e] = f2b(__expf(s * SCALE - CSHIFT));
            }
            pa[qt] = paq;
        }

        // PV (+ l via ones column): pa[qt] is the A-fragment in slot space
        __builtin_amdgcn_s_setprio(1);
        #pragma unroll
        for (int qt = 0; qt < 2; ++qt) {
            #pragma unroll
            for (int dt = 0; dt < 8; ++dt)
                oacc[qt][dt] = MFMA(pa[qt], vf[dt], oacc[qt][dt]);
            lacc[qt] = MFMA(pa[qt], vone, lacc[qt]);
        }
        __builtin_amdgcn_s_setprio(0);
    };

    #pragma unroll
    for (int it = 0; it < NTILES; it += 2) {
        tile_body(kbase + it * KT,       kf0, kf1, true,               kbase + (it + 1) * KT);
        tile_body(kbase + (it + 1) * KT, kf1, kf0, it + 2 < NTILES,    kbase + (it + 2) * KT);
    }

    // l: ones-column output is col-replicated; row q = g*4 + r (R3-proven D map)
    #pragma unroll
    for (int qt = 0; qt < 2; ++qt)
        if (ln == 0) {
            #pragma unroll
            for (int r = 0; r < 4; ++r)
                lpart[split * NN + q0 + qt * 16 + g * 4 + r] = lacc[qt][r];
        }

    // O partials -> bf16 via per-wave LDS bounce (coalesced 16B/lane stores)
    short* bounce = bounce_s + wave * 2048;   // 4KB/wave, wave-private
    #pragma unroll
    for (int qt = 0; qt < 2; ++qt) {
        #pragma unroll
        for (int dt = 0; dt < 8; ++dt)
            #pragma unroll
            for (int r = 0; r < 4; ++r)
                bounce[(g * 4 + r) * 128 + dt * 16 + ln] = f2b(oacc[qt][dt][r]);
        lds_fence();   // RAW: cross-lane bounce writes before row reads
        #pragma unroll
        for (int sub = 0; sub < 4; ++sub) {
            const int qrow = sub * 4 + (lane >> 4), chunk = lane & 15;
            const short8 rd = *(const short8*)&bounce[qrow * 128 + chunk * 8];
            *(short8*)&OpartB[((size_t)split * NN + q0 + qt * 16 + qrow) * HH + chunk * 8] = rd;
        }
        lds_fence();   // WAR before next qt overwrites the bounce
    }
}

// ===========================================================================
// Phase B: merge 16 bf16 partials -> msg; h_new = relu(msg@Wg+b_gcn+h_in(t));
// pred -> out[:,t]; h_proj(t+1) -> hp; h_in(t+1) -> hinT (recomputed, bf16-
// rounding parity; columns stored sigma-permuted). 256 blocks x 256 thr.
// ===========================================================================
__global__ __launch_bounds__(256) void fuse_kernel(
    const short* __restrict__ OpartB, const float* __restrict__ lpart,
    short* __restrict__ hp, short* __restrict__ hinT,
    const short* __restrict__ WgT, const short* __restrict__ WpT,
    const float* __restrict__ b_gcn, const float* __restrict__ b_proj,
    const float* __restrict__ W_out, const float* __restrict__ b_out,
    const float* __restrict__ x_seq, const float* __restrict__ m_seq,
    const float* __restrict__ W_in,  const float* __restrict__ b_in,
    float* __restrict__ out, int t)
{
    __shared__ __align__(16) short msgb[16 * 136];
    __shared__ __align__(16) short hnb[16 * 136];
    __shared__ __align__(16) short hintb[128 * 16];
    __shared__ float larr[16];
    __shared__ float ppd[4 * 16];

    const int tid = threadIdx.x;
    const int wave = tid >> 6, lane = tid & 63;
    const int ln = lane & 15, g = lane >> 4;
    const int qb = blockIdx.x * 16;

    if (tid < 16) {
        float l = 0.f;
        #pragma unroll
        for (int sp = 0; sp < SPLITS; ++sp) l += lpart[sp * NN + qb + tid];
        larr[tid] = 1.0f / l;
    }
    __syncthreads();

    // merge 16 bf16 partials -> msg (short8 coalesced reads, fp32 accumulate)
    {
        const int q = tid >> 4, c8 = (tid & 15) * 8;   // 256 thr = 16q x 16 chunks
        float s[8] = {0.f, 0.f, 0.f, 0.f, 0.f, 0.f, 0.f, 0.f};
        #pragma unroll
        for (int sp = 0; sp < SPLITS; ++sp) {
            const short8 v = *(const short8*)&OpartB[((size_t)sp * NN + qb + q) * HH + c8];
            #pragma unroll
            for (int k = 0; k < 8; ++k) s[k] += b2f(v[k]);
        }
        const float inv = larr[q];
        short* mp = &msgb[q * 136 + c8];
        #pragma unroll
        for (int k = 0; k < 8; ++k) mp[k] = f2b(s[k] * inv);
    }
    __syncthreads();

    // GEMM1: h_new = relu(msg @ W_gcn + b_gcn + h_in(t)); pred partials
    short8 af[4];
    #pragma unroll
    for (int kc = 0; kc < 4; ++kc)
        af[kc] = *(const short8*)&msgb[ln * 136 + kc * 32 + g * 8];
    float pr[4] = {0.f, 0.f, 0.f, 0.f};
    #pragma unroll
    for (int ni = 0; ni < 2; ++ni) {
        const int nt = wave * 2 + ni;
        f32x4 c = {};
        #pragma unroll
        for (int kc = 0; kc < 4; ++kc)
            c = MFMA(af[kc], *(const short8*)&WgT[(nt * 16 + ln) * HH + kc * 32 + g * 8], c);
        const int j = nt * 16 + ln;
        const float bg = b_gcn[j], wo = W_out[j];
        const float wj0 = W_in[j], wj1 = W_in[HH + j], bj = b_in[j];
        #pragma unroll
        for (int r = 0; r < 4; ++r) {
            const int q = g * 4 + r;
            float hv = x_seq[(qb + q) * TT + t] * wj0 + m_seq[(qb + q) * TT + t] * wj1 + bj;
            hv = hv > 0.f ? hv : 0.f;
            float v = c[r] + bg + b2f(f2b(hv));
            v = v > 0.f ? v : 0.f;
            hnb[q * 136 + j] = f2b(v);
            pr[r] += v * wo;
        }
    }
    #pragma unroll
    for (int r = 0; r < 4; ++r) {
        float p = pr[r];
        p += __shfl_xor(p, 1); p += __shfl_xor(p, 2);
        p += __shfl_xor(p, 4); p += __shfl_xor(p, 8);
        if (ln == 0) ppd[wave * 16 + g * 4 + r] = p;
    }
    __syncthreads();   // hnb + ppd complete

    if (tid < 16)
        out[(qb + tid) * TT + t] = ppd[tid] + ppd[16 + tid] + ppd[32 + tid] + ppd[48 + tid] + b_out[0];

    if (t < TT - 1) {
        // GEMM2: h_proj(t+1) = h_new @ W_proj + b_proj -> hp
        short8 hf[4];
        #pragma unroll
        for (int kc = 0; kc < 4; ++kc)
            hf[kc] = *(const short8*)&hnb[ln * 136 + kc * 32 + g * 8];
        #pragma unroll
        for (int ni = 0; ni < 2; ++ni) {
            const int nt = wave * 2 + ni;
            f32x4 c = {};
            #pragma unroll
            for (int kc = 0; kc < 4; ++kc)
                c = MFMA(hf[kc], *(const short8*)&WpT[(nt * 16 + ln) * HH + kc * 32 + g * 8], c);
            const float bp = b_proj[nt * 16 + ln];
            #pragma unroll
            for (int r = 0; r < 4; ++r)
                hp[(qb + g * 4 + r) * HH + nt * 16 + ln] = f2b(c[r] + bp);
        }

        // h_in(t+1): LDS transpose then 8B-chunk stores into sigma-permuted
        // hinT columns (inv_sigma maps aligned-4 chunks to aligned-4 chunks).
        for (int i = tid; i < 16 * HH; i += 256) {
            const int q = i >> 7, j = i & 127;
            float hv = x_seq[(qb + q) * TT + t + 1] * W_in[j]
                     + m_seq[(qb + q) * TT + t + 1] * W_in[HH + j] + b_in[j];
            hv = hv > 0.f ? hv : 0.f;
            hintb[j * 16 + q] = f2b(hv);
        }
        __syncthreads();
        for (int c = tid; c < 512; c += 256) {
            const int j = c >> 2, off = (c & 3) * 4;
            const int nb = qb + off;
            const int tcol = (nb & ~31) | (((nb >> 2) & 3) << 3) | (((nb >> 4) & 1) << 2);
            *(u64*)&hinT[(size_t)j * NNP + tcol] = *(const u64*)&hintb[j * 16 + off];
        }
    }
}

// ===========================================================================
extern "C" void kernel_launch(void* const* d_in, const int* in_sizes, int n_in,
                              void* d_out, int out_size, void* d_ws, size_t ws_size,
                              hipStream_t stream) {
    const float* x_seq  = (const float*)d_in[0];
    const float* m_seq  = (const float*)d_in[1];
    const float* W_in   = (const float*)d_in[2];
    const float* b_in   = (const float*)d_in[3];
    const float* W_proj = (const float*)d_in[4];
    const float* b_proj = (const float*)d_in[5];
    const float* W_gcn  = (const float*)d_in[6];
    const float* b_gcn  = (const float*)d_in[7];
    const float* W_out  = (const float*)d_in[8];
    const float* b_out  = (const float*)d_in[9];
    float* out = (float*)d_out;

    // ws carve (~20 MB): hp | hinT(padded) | WgT | WpT | lpart | OpartB
    char* base = (char*)d_ws;
    const size_t MB = 1 << 20;
    short* hp     = (short*)(base + 0 * MB);
    short* hinT   = (short*)(base + 1 * MB);           // 128*4160*2 B
    short* WgT    = (short*)(base + 3 * MB);
    short* WpT    = (short*)(base + 3 * MB + 32768);
    float* lpart  = (float*)(base + 3 * MB + 65536);   // 16*4096*4 = 256 KB
    short* OpartB = (short*)(base + 4 * MB);           // 16*4096*128*2 = 16 MB

    prep_kernel<<<272, 256, 0, stream>>>(x_seq, m_seq, W_in, b_in, W_proj, b_proj,
                                         W_gcn, hp, hinT, WgT, WpT);

    for (int t = 0; t < TT; ++t) {
        attn_kernel<<<(NN / 256) * SPLITS, 512, 0, stream>>>(hp, hinT, OpartB, lpart);
        fuse_kernel<<<NN / 16, 256, 0, stream>>>(OpartB, lpart, hp, hinT,
                                                 WgT, WpT, b_gcn, b_proj, W_out, b_out,
                                                 x_seq, m_seq, W_in, b_in, out, t);
    }
}